// Round 3
// baseline (655.347 us; speedup 1.0000x reference)
//
#include <hip/hip_runtime.h>

#define NN 50000
#define NE 600000
#define DD 128
#define XS 264   // k_update LDS row stride in u16 (unchanged, validated)
#define HS 40    // k_edges H ping-pong row stride in u16 (80B): b128 reads 16B-aligned, 2-way bank alias (free)

typedef unsigned short u16;
typedef u16   u16x8  __attribute__((ext_vector_type(8)));
typedef u16   u16x4  __attribute__((ext_vector_type(4)));
typedef __bf16 bf16x8 __attribute__((ext_vector_type(8)));
typedef float f32x4  __attribute__((ext_vector_type(4)));

__device__ __forceinline__ u16 f2bf(float f) {  // RNE fp32->bf16
    unsigned u = __builtin_bit_cast(unsigned, f);
    u += 0x7FFFu + ((u >> 16) & 1u);
    return (u16)(u >> 16);
}

// node_features fp32 [NN,DD] -> bf16 table
__global__ void k_convert_nf(const float* __restrict__ nf, u16* __restrict__ out) {
    int id = blockIdx.x * 256 + threadIdx.x;            // NN*DD/4 threads exactly
    float4 v = ((const float4*)nf)[id];
    u16x4 o; o[0] = f2bf(v.x); o[1] = f2bf(v.y); o[2] = f2bf(v.z); o[3] = f2bf(v.w);
    ((u16x4*)out)[id] = o;
}

// Pack W[K,N] fp32 row-major into MFMA B-fragment order for 16x16x32:
// frag = nt*KT + kt (KT = K/32); within frag: lane*8 + j holds
// W[kt*32 + (lane>>4)*8 + j][nt*16 + (lane&15)]
__global__ void k_pack(const float* __restrict__ W, u16* __restrict__ out, int K, int N) {
    int tid = blockIdx.x * 256 + threadIdx.x;
    if (tid >= K * N) return;
    int frag = tid >> 9, lane = (tid >> 3) & 63, j = tid & 7;
    int KT = K >> 5;
    int nt = frag / KT, kt = frag - nt * KT;
    int row = kt * 32 + ((lane >> 4) << 3) + j;
    int col = nt * 16 + (lane & 15);
    out[tid] = f2bf(W[row * N + col]);
}

// ---------------- edge kernel v3: 1 wave/block, 1 tile/block, layer-interleaved ----------------
// A-frag gather direct from global (HW-validated round 0/2): lane (quad,l15), elem j =
//   kt<4 : nf16[from*128 + kt*32 + quad*8 + j],  kt>=4 : nf16[to*128 + (kt-4)*32 + quad*8 + j]
// Layer fusion: layer-1 k-tile p consumes exactly the H columns produced by layer-0 nt-pair
// {2p,2p+1}, so only a 32x32 bf16 transpose ping-pong lives in LDS (2,560 B). No barriers
// (single wave, in-order DS pipe). Occupancy is VGPR-bound: __launch_bounds__(64,3) -> 12 waves/CU.

__device__ __forceinline__ void load_eidx(const int* __restrict__ from_idx,
                                          const int* __restrict__ to_idx,
                                          int e0, int l15, int (&fm)[2], int (&tn)[2]) {
    #pragma unroll
    for (int mt = 0; mt < 2; ++mt) {
        int e = e0 + mt * 16 + l15;
        fm[mt] = from_idx[e];
        tn[mt] = to_idx[e];
    }
}

__device__ __forceinline__ void gather_frags(bf16x8 (&a)[2][8], const u16* __restrict__ nf16,
                                             const int (&fm)[2], const int (&tn)[2], int q8) {
    #pragma unroll
    for (int mt = 0; mt < 2; ++mt) {
        const u16* rf = nf16 + (size_t)fm[mt] * DD + q8;
        const u16* rt = nf16 + (size_t)tn[mt] * DD + q8;
        #pragma unroll
        for (int kt = 0; kt < 4; ++kt) {
            a[mt][kt]     = __builtin_bit_cast(bf16x8, *(const u16x8*)(rf + kt * 32));
            a[mt][kt + 4] = __builtin_bit_cast(bf16x8, *(const u16x8*)(rt + kt * 32));
        }
    }
}

__global__ __launch_bounds__(64, 3) void k_edges(
    const u16* __restrict__ nf16, const int* __restrict__ from_idx,
    const int* __restrict__ to_idx, const u16* __restrict__ pW0,
    const float* __restrict__ b0, const u16* __restrict__ pW1,
    const float* __restrict__ b1, float* __restrict__ agg)
{
    __shared__ u16 sH[32 * HS];   // 2,560 B: 32x32 H-column ping-pong (wave-private)
    const int lane = threadIdx.x; // 64 threads = 1 wave
    const int l15  = lane & 15;
    const int quad = lane >> 4;
    const int q8   = quad * 8;
    const int e0 = blockIdx.x * 32;

    int fm[2], tn[2];
    load_eidx(from_idx, to_idx, e0, l15, fm, tn);
    bf16x8 A[2][8];
    gather_frags(A, nf16, fm, tn, q8);   // all 16 frags first-used in pair 0: compiler can't sink

    f32x4 acc[2][8];   // layer-1 accumulators: [mt][nt1]
    #pragma unroll
    for (int mt = 0; mt < 2; ++mt)
        #pragma unroll
        for (int nt = 0; nt < 8; ++nt)
            acc[mt][nt] = (f32x4){0.f, 0.f, 0.f, 0.f};

    for (int p = 0; p < 8; ++p) {        // 8 pairs: layer-0 cols {2p,2p+1}*16, layer-1 k-tile p
        // layer 0 on this nt-pair
        f32x4 c[2][2];                   // [s = nt&1][mt]
        #pragma unroll
        for (int s = 0; s < 2; ++s)
            #pragma unroll
            for (int mt = 0; mt < 2; ++mt)
                c[s][mt] = (f32x4){0.f, 0.f, 0.f, 0.f};
        #pragma unroll
        for (int kt = 0; kt < 8; ++kt) {
            bf16x8 b = __builtin_bit_cast(bf16x8, *(const u16x8*)(pW0 + ((2 * p) * 8 + kt) * 512 + lane * 8));
            c[0][0] = __builtin_amdgcn_mfma_f32_16x16x32_bf16(A[0][kt], b, c[0][0], 0, 0, 0);
            c[0][1] = __builtin_amdgcn_mfma_f32_16x16x32_bf16(A[1][kt], b, c[0][1], 0, 0, 0);
            b = __builtin_bit_cast(bf16x8, *(const u16x8*)(pW0 + ((2 * p + 1) * 8 + kt) * 512 + lane * 8));
            c[1][0] = __builtin_amdgcn_mfma_f32_16x16x32_bf16(A[0][kt], b, c[1][0], 0, 0, 0);
            c[1][1] = __builtin_amdgcn_mfma_f32_16x16x32_bf16(A[1][kt], b, c[1][1], 0, 0, 0);
        }
        // relu + bf16 + transpose through the 32x32 ping-pong
        #pragma unroll
        for (int s = 0; s < 2; ++s) {
            float bias = b0[(2 * p + s) * 16 + l15];
            #pragma unroll
            for (int mt = 0; mt < 2; ++mt)
                #pragma unroll
                for (int i = 0; i < 4; ++i)
                    sH[(mt * 16 + quad * 4 + i) * HS + s * 16 + l15] = f2bf(fmaxf(c[s][mt][i] + bias, 0.f));
        }
        // layer-1 A-frags for k-tile p (same wave wrote; in-order DS pipe, no barrier)
        bf16x8 a1[2];
        #pragma unroll
        for (int mt = 0; mt < 2; ++mt)
            a1[mt] = __builtin_bit_cast(bf16x8, *(const u16x8*)(&sH[(mt * 16 + l15) * HS + q8]));
        // layer-1 partial accumulation
        #pragma unroll
        for (int nt = 0; nt < 8; ++nt) {
            bf16x8 b = __builtin_bit_cast(bf16x8, *(const u16x8*)(pW1 + (nt * 8 + p) * 512 + lane * 8));
            acc[0][nt] = __builtin_amdgcn_mfma_f32_16x16x32_bf16(a1[0], b, acc[0][nt], 0, 0, 0);
            acc[1][nt] = __builtin_amdgcn_mfma_f32_16x16x32_bf16(a1[1], b, acc[1][nt], 0, 0, 0);
        }
    }

    // scatter-add into agg (fire-and-forget atomics)
    int tI[2][4];
    #pragma unroll
    for (int mt = 0; mt < 2; ++mt)
        #pragma unroll
        for (int i = 0; i < 4; ++i)
            tI[mt][i] = to_idx[e0 + mt * 16 + quad * 4 + i];
    #pragma unroll
    for (int nt = 0; nt < 8; ++nt) {
        float bias = b1[nt * 16 + l15];
        int col = nt * 16 + l15;
        #pragma unroll
        for (int i = 0; i < 4; ++i) {
            unsafeAtomicAdd(&agg[(size_t)tI[0][i] * DD + col], fmaxf(acc[0][nt][i] + bias, 0.f));
            unsafeAtomicAdd(&agg[(size_t)tI[1][i] * DD + col], fmaxf(acc[1][nt][i] + bias, 0.f));
        }
    }
}

// Node update: out = nf + relu(relu([agg|nf] @ uW0 + ub0) @ uW1 + ub1)   (unchanged, validated)
__global__ __launch_bounds__(128) void k_update(
    const float* __restrict__ agg, const u16* __restrict__ nf16,
    const float* __restrict__ nf32, const u16* __restrict__ pW0,
    const float* __restrict__ b0, const u16* __restrict__ pW1,
    const float* __restrict__ b1, float* __restrict__ out)
{
    __shared__ u16 sX[64 * XS];
    const int tid = threadIdx.x;
    const int n0 = blockIdx.x * 64;

    // stage agg half (cols 0..127), fp32->bf16
    #pragma unroll
    for (int i = 0; i < 16; ++i) {
        int c = i * 128 + tid;
        int r = c >> 5, j = c & 31;
        int n = n0 + r;
        u16x4 o;
        if (n < NN) {
            float4 v = *(const float4*)(agg + (size_t)n * DD + j * 4);
            o[0] = f2bf(v.x); o[1] = f2bf(v.y); o[2] = f2bf(v.z); o[3] = f2bf(v.w);
        } else { o[0] = 0; o[1] = 0; o[2] = 0; o[3] = 0; }
        *(u16x4*)(&sX[r * XS + j * 4]) = o;
    }
    // stage nf half (cols 128..255), bf16 copy
    #pragma unroll
    for (int i = 0; i < 8; ++i) {
        int c = i * 128 + tid;
        int r = c >> 4, j = c & 15;
        int n = n0 + r;
        u16x8 v = {0, 0, 0, 0, 0, 0, 0, 0};
        if (n < NN) v = *(const u16x8*)(nf16 + (size_t)n * DD + j * 8);
        *(u16x8*)(&sX[r * XS + 128 + j * 8]) = v;
    }
    __syncthreads();

    const int lane = tid & 63;
    const int wave = tid >> 6;
    const int base = wave * 32;
    const int l15  = lane & 15;
    const int quad = lane >> 4;
    const int arow0 = (base + l15) * XS + quad * 8;

    bf16x8 a[2][8];
    #pragma unroll
    for (int mt = 0; mt < 2; ++mt)
        #pragma unroll
        for (int kt = 0; kt < 8; ++kt)
            a[mt][kt] = __builtin_bit_cast(bf16x8, *(const u16x8*)(&sX[arow0 + mt * 16 * XS + kt * 32]));

    for (int nt = 0; nt < 16; ++nt) {
        f32x4 c0 = {0.f, 0.f, 0.f, 0.f}, c1 = {0.f, 0.f, 0.f, 0.f};
        #pragma unroll
        for (int kt = 0; kt < 8; ++kt) {
            bf16x8 b = __builtin_bit_cast(bf16x8, *(const u16x8*)(pW0 + (nt * 8 + kt) * 512 + lane * 8));
            c0 = __builtin_amdgcn_mfma_f32_16x16x32_bf16(a[0][kt], b, c0, 0, 0, 0);
            c1 = __builtin_amdgcn_mfma_f32_16x16x32_bf16(a[1][kt], b, c1, 0, 0, 0);
        }
        float bias = b0[nt * 16 + l15];
        #pragma unroll
        for (int i = 0; i < 4; ++i) {
            sX[(base +      quad * 4 + i) * XS + nt * 16 + l15] = f2bf(fmaxf(c0[i] + bias, 0.f));
            sX[(base + 16 + quad * 4 + i) * XS + nt * 16 + l15] = f2bf(fmaxf(c1[i] + bias, 0.f));
        }
    }

    #pragma unroll
    for (int mt = 0; mt < 2; ++mt)
        #pragma unroll
        for (int kt = 0; kt < 8; ++kt)
            a[mt][kt] = __builtin_bit_cast(bf16x8, *(const u16x8*)(&sX[arow0 + mt * 16 * XS + kt * 32]));

    for (int nt = 0; nt < 8; ++nt) {
        f32x4 c0 = {0.f, 0.f, 0.f, 0.f}, c1 = {0.f, 0.f, 0.f, 0.f};
        #pragma unroll
        for (int kt = 0; kt < 8; ++kt) {
            bf16x8 b = __builtin_bit_cast(bf16x8, *(const u16x8*)(pW1 + (nt * 8 + kt) * 512 + lane * 8));
            c0 = __builtin_amdgcn_mfma_f32_16x16x32_bf16(a[0][kt], b, c0, 0, 0, 0);
            c1 = __builtin_amdgcn_mfma_f32_16x16x32_bf16(a[1][kt], b, c1, 0, 0, 0);
        }
        float bias = b1[nt * 16 + l15];
        int col = nt * 16 + l15;
        #pragma unroll
        for (int i = 0; i < 4; ++i) {
            int na = n0 + base +      quad * 4 + i;
            int nb = n0 + base + 16 + quad * 4 + i;
            if (na < NN) out[(size_t)na * DD + col] = nf32[(size_t)na * DD + col] + fmaxf(c0[i] + bias, 0.f);
            if (nb < NN) out[(size_t)nb * DD + col] = nf32[(size_t)nb * DD + col] + fmaxf(c1[i] + bias, 0.f);
        }
    }
}

extern "C" void kernel_launch(void* const* d_in, const int* in_sizes, int n_in,
                              void* d_out, int out_size, void* d_ws, size_t ws_size,
                              hipStream_t stream)
{
    const float* nf  = (const float*)d_in[0];
    const int* fidx  = (const int*)d_in[1];
    const int* tidx  = (const int*)d_in[2];
    const float* mW0 = (const float*)d_in[3];
    const float* mb0 = (const float*)d_in[4];
    const float* mW1 = (const float*)d_in[5];
    const float* mb1 = (const float*)d_in[6];
    const float* uW0 = (const float*)d_in[7];
    const float* ub0 = (const float*)d_in[8];
    const float* uW1 = (const float*)d_in[9];
    const float* ub1 = (const float*)d_in[10];
    float* out = (float*)d_out;

    char* ws = (char*)d_ws;
    u16*   nf16 = (u16*)ws;   ws += (size_t)NN * DD * 2;   // 12.8 MB
    float* agg  = (float*)ws; ws += (size_t)NN * DD * 4;   // 25.6 MB
    u16*   pmW0 = (u16*)ws;   ws += 256 * 256 * 2;
    u16*   pmW1 = (u16*)ws;   ws += 256 * 128 * 2;
    u16*   puW0 = (u16*)ws;   ws += 256 * 256 * 2;
    u16*   puW1 = (u16*)ws;   ws += 256 * 128 * 2;

    hipMemsetAsync(agg, 0, (size_t)NN * DD * 4, stream);
    k_convert_nf<<<(NN * DD / 4) / 256, 256, 0, stream>>>(nf, nf16);
    k_pack<<<256, 256, 0, stream>>>(mW0, pmW0, 256, 256);
    k_pack<<<128, 256, 0, stream>>>(mW1, pmW1, 256, 128);
    k_pack<<<256, 256, 0, stream>>>(uW0, puW0, 256, 256);
    k_pack<<<128, 256, 0, stream>>>(uW1, puW1, 256, 128);
    k_edges<<<NE / 32, 64, 0, stream>>>(nf16, fidx, tidx, pmW0, mb0, pmW1, mb1, agg);
    k_update<<<(NN + 63) / 64, 128, 0, stream>>>(agg, nf16, nf, puW0, ub0, puW1, ub1, out);
}

// Round 5
// 648.237 us; speedup vs baseline: 1.0110x; 1.0110x over previous
//
#include <hip/hip_runtime.h>

#define NN 50000
#define NE 600000
#define DD 128
#define XS 264   // padded LDS row stride in bf16 elems: 528 B = 33*16 (16B aligned), %32-dword offset 4 -> 2-way bank alias (free)

typedef unsigned short u16;
typedef u16   u16x8  __attribute__((ext_vector_type(8)));
typedef u16   u16x4  __attribute__((ext_vector_type(4)));
typedef __bf16 bf16x8 __attribute__((ext_vector_type(8)));
typedef float f32x4  __attribute__((ext_vector_type(4)));

__device__ __forceinline__ u16 f2bf(float f) {  // RNE fp32->bf16
    unsigned u = __builtin_bit_cast(unsigned, f);
    u += 0x7FFFu + ((u >> 16) & 1u);
    return (u16)(u >> 16);
}

// node_features fp32 [NN,DD] -> bf16 table
__global__ void k_convert_nf(const float* __restrict__ nf, u16* __restrict__ out) {
    int id = blockIdx.x * 256 + threadIdx.x;            // NN*DD/4 threads exactly
    float4 v = ((const float4*)nf)[id];
    u16x4 o; o[0] = f2bf(v.x); o[1] = f2bf(v.y); o[2] = f2bf(v.z); o[3] = f2bf(v.w);
    ((u16x4*)out)[id] = o;
}

// Pack W[K,N] fp32 row-major into MFMA B-fragment order for 16x16x32:
// frag = nt*KT + kt (KT = K/32); within frag: lane*8 + j holds
// W[kt*32 + (lane>>4)*8 + j][nt*16 + (lane&15)]
__global__ void k_pack(const float* __restrict__ W, u16* __restrict__ out, int K, int N) {
    int tid = blockIdx.x * 256 + threadIdx.x;
    if (tid >= K * N) return;
    int frag = tid >> 9, lane = (tid >> 3) & 63, j = tid & 7;
    int KT = K >> 5;
    int nt = frag / KT, kt = frag - nt * KT;
    int row = kt * 32 + ((lane >> 4) << 3) + j;
    int col = nt * 16 + (lane & 15);
    out[tid] = f2bf(W[row * N + col]);
}

// ---------------- edge kernel v4: v1 skeleton, 4 waves / 128 edges per block ----------------
// v1's validated structure (fastest measured: 365us at 64 edges/block): cooperative LDS X
// staging + barrier + phase-separated L0 -> H(LDS) -> L1 per wave (32 rows each).
// Change vs v1: 2x edges per gather/barrier phase (128), halving per-edge gather-wait count.
// LDS 67.6KB -> 2 blocks/CU = 8 waves/CU (same concurrency as v1, fewer serial phases).
__global__ __launch_bounds__(256, 2) void k_edges(
    const u16* __restrict__ nf16, const int* __restrict__ from_idx,
    const int* __restrict__ to_idx, const u16* __restrict__ pW0,
    const float* __restrict__ b0, const u16* __restrict__ pW1,
    const float* __restrict__ b1, float* __restrict__ agg)
{
    __shared__ u16 sX[128 * XS];   // 67,584 B
    const int tid = threadIdx.x;
    const int e0 = blockIdx.x * 128;

    // stage gather: 128 rows x 32 chunks of 8 bf16 (16 B); clamp tail reads
    #pragma unroll
    for (int i = 0; i < 16; ++i) {
        int c = i * 256 + tid;
        int r = c >> 5, j = c & 31;
        int e = e0 + r; if (e >= NE) e = NE - 1;
        int node = (j < 16) ? from_idx[e] : to_idx[e];
        *(u16x8*)(&sX[r * XS + j * 8]) = *(const u16x8*)(nf16 + node * DD + (j & 15) * 8);
    }
    __syncthreads();

    const int lane = tid & 63;
    const int wave = tid >> 6;
    const int base = wave * 32;
    const int l15  = lane & 15;
    const int quad = lane >> 4;
    const int arow0 = (base + l15) * XS + quad * 8;

    // consume X fully into registers (A-frags), freeing sX rows for H (rows wave-private)
    bf16x8 a[2][8];
    #pragma unroll
    for (int mt = 0; mt < 2; ++mt)
        #pragma unroll
        for (int kt = 0; kt < 8; ++kt)
            a[mt][kt] = __builtin_bit_cast(bf16x8, *(const u16x8*)(&sX[arow0 + mt * 16 * XS + kt * 32]));

    // layer 0: H[128,256] = relu(X @ W0 + b0); independent nt iterations -> compiler pipelines B loads
    for (int nt = 0; nt < 16; ++nt) {
        f32x4 c0 = {0.f, 0.f, 0.f, 0.f}, c1 = {0.f, 0.f, 0.f, 0.f};
        #pragma unroll
        for (int kt = 0; kt < 8; ++kt) {
            bf16x8 b = __builtin_bit_cast(bf16x8, *(const u16x8*)(pW0 + (nt * 8 + kt) * 512 + lane * 8));
            c0 = __builtin_amdgcn_mfma_f32_16x16x32_bf16(a[0][kt], b, c0, 0, 0, 0);
            c1 = __builtin_amdgcn_mfma_f32_16x16x32_bf16(a[1][kt], b, c1, 0, 0, 0);
        }
        float bias = b0[nt * 16 + l15];
        #pragma unroll
        for (int i = 0; i < 4; ++i) {
            sX[(base +      quad * 4 + i) * XS + nt * 16 + l15] = f2bf(fmaxf(c0[i] + bias, 0.f));
            sX[(base + 16 + quad * 4 + i) * XS + nt * 16 + l15] = f2bf(fmaxf(c1[i] + bias, 0.f));
        }
    }

    // layer 1 A-frags from H (same rows, in-wave ordered: no barrier needed)
    #pragma unroll
    for (int mt = 0; mt < 2; ++mt)
        #pragma unroll
        for (int kt = 0; kt < 8; ++kt)
            a[mt][kt] = __builtin_bit_cast(bf16x8, *(const u16x8*)(&sX[arow0 + mt * 16 * XS + kt * 32]));

    // scatter indices early (latency hidden under layer-1 MFMAs); guard tail
    int tI[2][4];
    int eV[2][4];
    #pragma unroll
    for (int mt = 0; mt < 2; ++mt)
        #pragma unroll
        for (int i = 0; i < 4; ++i) {
            int e = e0 + base + mt * 16 + quad * 4 + i;
            eV[mt][i] = e;
            tI[mt][i] = to_idx[e < NE ? e : NE - 1];
        }

    // layer 1: m = relu(H @ W1 + b1), scatter-add into agg
    for (int nt = 0; nt < 8; ++nt) {
        f32x4 c0 = {0.f, 0.f, 0.f, 0.f}, c1 = {0.f, 0.f, 0.f, 0.f};
        #pragma unroll
        for (int kt = 0; kt < 8; ++kt) {
            bf16x8 b = __builtin_bit_cast(bf16x8, *(const u16x8*)(pW1 + (nt * 8 + kt) * 512 + lane * 8));
            c0 = __builtin_amdgcn_mfma_f32_16x16x32_bf16(a[0][kt], b, c0, 0, 0, 0);
            c1 = __builtin_amdgcn_mfma_f32_16x16x32_bf16(a[1][kt], b, c1, 0, 0, 0);
        }
        float bias = b1[nt * 16 + l15];
        int col = nt * 16 + l15;
        #pragma unroll
        for (int i = 0; i < 4; ++i) {
            if (eV[0][i] < NE) unsafeAtomicAdd(&agg[(size_t)tI[0][i] * DD + col], fmaxf(c0[i] + bias, 0.f));
            if (eV[1][i] < NE) unsafeAtomicAdd(&agg[(size_t)tI[1][i] * DD + col], fmaxf(c1[i] + bias, 0.f));
        }
    }
}

// Node update: out = nf + relu(relu([agg|nf] @ uW0 + ub0) @ uW1 + ub1)   (unchanged, validated)
__global__ __launch_bounds__(128) void k_update(
    const float* __restrict__ agg, const u16* __restrict__ nf16,
    const float* __restrict__ nf32, const u16* __restrict__ pW0,
    const float* __restrict__ b0, const u16* __restrict__ pW1,
    const float* __restrict__ b1, float* __restrict__ out)
{
    __shared__ u16 sX[64 * XS];
    const int tid = threadIdx.x;
    const int n0 = blockIdx.x * 64;

    // stage agg half (cols 0..127), fp32->bf16
    #pragma unroll
    for (int i = 0; i < 16; ++i) {
        int c = i * 128 + tid;
        int r = c >> 5, j = c & 31;
        int n = n0 + r;
        u16x4 o;
        if (n < NN) {
            float4 v = *(const float4*)(agg + (size_t)n * DD + j * 4);
            o[0] = f2bf(v.x); o[1] = f2bf(v.y); o[2] = f2bf(v.z); o[3] = f2bf(v.w);
        } else { o[0] = 0; o[1] = 0; o[2] = 0; o[3] = 0; }
        *(u16x4*)(&sX[r * XS + j * 4]) = o;
    }
    // stage nf half (cols 128..255), bf16 copy
    #pragma unroll
    for (int i = 0; i < 8; ++i) {
        int c = i * 128 + tid;
        int r = c >> 4, j = c & 15;
        int n = n0 + r;
        u16x8 v = {0, 0, 0, 0, 0, 0, 0, 0};
        if (n < NN) v = *(const u16x8*)(nf16 + (size_t)n * DD + j * 8);
        *(u16x8*)(&sX[r * XS + 128 + j * 8]) = v;
    }
    __syncthreads();

    const int lane = tid & 63;
    const int wave = tid >> 6;
    const int base = wave * 32;
    const int l15  = lane & 15;
    const int quad = lane >> 4;
    const int arow0 = (base + l15) * XS + quad * 8;

    bf16x8 a[2][8];
    #pragma unroll
    for (int mt = 0; mt < 2; ++mt)
        #pragma unroll
        for (int kt = 0; kt < 8; ++kt)
            a[mt][kt] = __builtin_bit_cast(bf16x8, *(const u16x8*)(&sX[arow0 + mt * 16 * XS + kt * 32]));

    for (int nt = 0; nt < 16; ++nt) {
        f32x4 c0 = {0.f, 0.f, 0.f, 0.f}, c1 = {0.f, 0.f, 0.f, 0.f};
        #pragma unroll
        for (int kt = 0; kt < 8; ++kt) {
            bf16x8 b = __builtin_bit_cast(bf16x8, *(const u16x8*)(pW0 + (nt * 8 + kt) * 512 + lane * 8));
            c0 = __builtin_amdgcn_mfma_f32_16x16x32_bf16(a[0][kt], b, c0, 0, 0, 0);
            c1 = __builtin_amdgcn_mfma_f32_16x16x32_bf16(a[1][kt], b, c1, 0, 0, 0);
        }
        float bias = b0[nt * 16 + l15];
        #pragma unroll
        for (int i = 0; i < 4; ++i) {
            sX[(base +      quad * 4 + i) * XS + nt * 16 + l15] = f2bf(fmaxf(c0[i] + bias, 0.f));
            sX[(base + 16 + quad * 4 + i) * XS + nt * 16 + l15] = f2bf(fmaxf(c1[i] + bias, 0.f));
        }
    }

    #pragma unroll
    for (int mt = 0; mt < 2; ++mt)
        #pragma unroll
        for (int kt = 0; kt < 8; ++kt)
            a[mt][kt] = __builtin_bit_cast(bf16x8, *(const u16x8*)(&sX[arow0 + mt * 16 * XS + kt * 32]));

    for (int nt = 0; nt < 8; ++nt) {
        f32x4 c0 = {0.f, 0.f, 0.f, 0.f}, c1 = {0.f, 0.f, 0.f, 0.f};
        #pragma unroll
        for (int kt = 0; kt < 8; ++kt) {
            bf16x8 b = __builtin_bit_cast(bf16x8, *(const u16x8*)(pW1 + (nt * 8 + kt) * 512 + lane * 8));
            c0 = __builtin_amdgcn_mfma_f32_16x16x32_bf16(a[0][kt], b, c0, 0, 0, 0);
            c1 = __builtin_amdgcn_mfma_f32_16x16x32_bf16(a[1][kt], b, c1, 0, 0, 0);
        }
        float bias = b1[nt * 16 + l15];
        int col = nt * 16 + l15;
        #pragma unroll
        for (int i = 0; i < 4; ++i) {
            int na = n0 + base +      quad * 4 + i;
            int nb = n0 + base + 16 + quad * 4 + i;
            if (na < NN) out[(size_t)na * DD + col] = nf32[(size_t)na * DD + col] + fmaxf(c0[i] + bias, 0.f);
            if (nb < NN) out[(size_t)nb * DD + col] = nf32[(size_t)nb * DD + col] + fmaxf(c1[i] + bias, 0.f);
        }
    }
}

extern "C" void kernel_launch(void* const* d_in, const int* in_sizes, int n_in,
                              void* d_out, int out_size, void* d_ws, size_t ws_size,
                              hipStream_t stream)
{
    const float* nf  = (const float*)d_in[0];
    const int* fidx  = (const int*)d_in[1];
    const int* tidx  = (const int*)d_in[2];
    const float* mW0 = (const float*)d_in[3];
    const float* mb0 = (const float*)d_in[4];
    const float* mW1 = (const float*)d_in[5];
    const float* mb1 = (const float*)d_in[6];
    const float* uW0 = (const float*)d_in[7];
    const float* ub0 = (const float*)d_in[8];
    const float* uW1 = (const float*)d_in[9];
    const float* ub1 = (const float*)d_in[10];
    float* out = (float*)d_out;

    char* ws = (char*)d_ws;
    u16*   nf16 = (u16*)ws;   ws += (size_t)NN * DD * 2;   // 12.8 MB
    float* agg  = (float*)ws; ws += (size_t)NN * DD * 4;   // 25.6 MB
    u16*   pmW0 = (u16*)ws;   ws += 256 * 256 * 2;
    u16*   pmW1 = (u16*)ws;   ws += 256 * 128 * 2;
    u16*   puW0 = (u16*)ws;   ws += 256 * 256 * 2;
    u16*   puW1 = (u16*)ws;   ws += 256 * 128 * 2;

    hipMemsetAsync(agg, 0, (size_t)NN * DD * 4, stream);
    k_convert_nf<<<(NN * DD / 4) / 256, 256, 0, stream>>>(nf, nf16);
    k_pack<<<256, 256, 0, stream>>>(mW0, pmW0, 256, 256);
    k_pack<<<128, 256, 0, stream>>>(mW1, pmW1, 256, 128);
    k_pack<<<256, 256, 0, stream>>>(uW0, puW0, 256, 256);
    k_pack<<<128, 256, 0, stream>>>(uW1, puW1, 256, 128);
    k_edges<<<(NE + 127) / 128, 256, 0, stream>>>(nf16, fidx, tidx, pmW0, mb0, pmW1, mb1, agg);
    k_update<<<(NN + 63) / 64, 128, 0, stream>>>(agg, nf16, nf, puW0, ub0, puW1, ub1, out);
}

// Round 6
// 589.737 us; speedup vs baseline: 1.1113x; 1.0992x over previous
//
#include <hip/hip_runtime.h>

#define NN 50000
#define NE 600000
#define DD 128
#define XS 264   // padded LDS row stride in bf16 elems: 528 B = 33*16 (16B aligned), %32-dword offset 4 -> 2-way bank alias (free)

typedef unsigned short u16;
typedef u16   u16x8  __attribute__((ext_vector_type(8)));
typedef u16   u16x4  __attribute__((ext_vector_type(4)));
typedef __bf16 bf16x8 __attribute__((ext_vector_type(8)));
typedef float f32x4  __attribute__((ext_vector_type(4)));

__device__ __forceinline__ u16 f2bf(float f) {  // RNE fp32->bf16
    unsigned u = __builtin_bit_cast(unsigned, f);
    u += 0x7FFFu + ((u >> 16) & 1u);
    return (u16)(u >> 16);
}

// node_features fp32 [NN,DD] -> bf16 table
__global__ void k_convert_nf(const float* __restrict__ nf, u16* __restrict__ out) {
    int id = blockIdx.x * 256 + threadIdx.x;            // NN*DD/4 threads exactly
    float4 v = ((const float4*)nf)[id];
    u16x4 o; o[0] = f2bf(v.x); o[1] = f2bf(v.y); o[2] = f2bf(v.z); o[3] = f2bf(v.w);
    ((u16x4*)out)[id] = o;
}

// Pack W[K,N] fp32 row-major into MFMA B-fragment order for 16x16x32
__global__ void k_pack(const float* __restrict__ W, u16* __restrict__ out, int K, int N) {
    int tid = blockIdx.x * 256 + threadIdx.x;
    if (tid >= K * N) return;
    int frag = tid >> 9, lane = (tid >> 3) & 63, j = tid & 7;
    int KT = K >> 5;
    int nt = frag / KT, kt = frag - nt * KT;
    int row = kt * 32 + ((lane >> 4) << 3) + j;
    int col = nt * 16 + (lane & 15);
    out[tid] = f2bf(W[row * N + col]);
}

// ---------------- counting sort of edges by destination ----------------
__global__ void k_hist(const int* __restrict__ to_idx, int* __restrict__ cnt) {
    int e = blockIdx.x * 256 + threadIdx.x;
    if (e < NE) atomicAdd(&cnt[to_idx[e]], 1);
}

// single-block exclusive scan of cnt[0..NN) -> cursor (chunked Hillis-Steele, 1024 threads)
__global__ void k_scan(const int* __restrict__ cnt, int* __restrict__ cursor) {
    __shared__ int s[1024];
    __shared__ int carry_s;
    int tid = threadIdx.x;
    if (tid == 0) carry_s = 0;
    __syncthreads();
    for (int base = 0; base < NN; base += 1024) {
        int v = (base + tid < NN) ? cnt[base + tid] : 0;
        s[tid] = v;
        __syncthreads();
        for (int ofs = 1; ofs < 1024; ofs <<= 1) {
            int t = (tid >= ofs) ? s[tid - ofs] : 0;
            __syncthreads();
            s[tid] += t;
            __syncthreads();
        }
        int carry = carry_s;                       // uniform read, pre-update
        if (base + tid < NN) cursor[base + tid] = carry + s[tid] - v;   // exclusive
        __syncthreads();
        if (tid == 0) carry_s = carry + s[1023];
        __syncthreads();
    }
}

__global__ void k_reorder(const int* __restrict__ from_idx, const int* __restrict__ to_idx,
                          int* __restrict__ cursor, int* __restrict__ sf, int* __restrict__ st) {
    int e = blockIdx.x * 256 + threadIdx.x;
    if (e < NE) {
        int d = to_idx[e];
        int p = atomicAdd(&cursor[d], 1);
        sf[p] = from_idx[e];
        st[p] = d;
    }
}

// ---------------- edge kernel v5: v1 geometry (fastest validated) on dest-sorted edges ----------------
// 64 edges/block, 128 threads (2 waves), wave owns 32 rows. Sorted edges => each lane's 4
// consecutive rows mostly share a destination (avg run 12): register run-dedup collapses
// atomics ~3x and clusters remaining atomics on temporally-adjacent blocks (L2-coalescible).
__global__ __launch_bounds__(128) void k_edges(
    const u16* __restrict__ nf16, const int* __restrict__ sf,
    const int* __restrict__ st, const u16* __restrict__ pW0,
    const float* __restrict__ b0, const u16* __restrict__ pW1,
    const float* __restrict__ b1, float* __restrict__ agg)
{
    __shared__ u16 sX[64 * XS];
    const int tid = threadIdx.x;
    const int e0 = blockIdx.x * 64;

    // stage gather: 64 rows x 32 chunks of 8 bf16 (16 B); to-side rows repeat (sorted) -> cache-hot
    #pragma unroll
    for (int i = 0; i < 16; ++i) {
        int c = i * 128 + tid;
        int r = c >> 5, j = c & 31;
        int e = e0 + r;
        int node = (j < 16) ? sf[e] : st[e];
        *(u16x8*)(&sX[r * XS + j * 8]) = *(const u16x8*)(nf16 + node * DD + (j & 15) * 8);
    }
    __syncthreads();

    const int lane = tid & 63;
    const int wave = tid >> 6;
    const int base = wave * 32;
    const int l15  = lane & 15;
    const int quad = lane >> 4;
    const int arow0 = (base + l15) * XS + quad * 8;

    // consume X fully into registers (A-frags), freeing sX rows for H (rows wave-private)
    bf16x8 a[2][8];
    #pragma unroll
    for (int mt = 0; mt < 2; ++mt)
        #pragma unroll
        for (int kt = 0; kt < 8; ++kt)
            a[mt][kt] = __builtin_bit_cast(bf16x8, *(const u16x8*)(&sX[arow0 + mt * 16 * XS + kt * 32]));

    // layer 0: H[64,256] = relu(X @ W0 + b0)
    for (int nt = 0; nt < 16; ++nt) {
        f32x4 c0 = {0.f, 0.f, 0.f, 0.f}, c1 = {0.f, 0.f, 0.f, 0.f};
        #pragma unroll
        for (int kt = 0; kt < 8; ++kt) {
            bf16x8 b = __builtin_bit_cast(bf16x8, *(const u16x8*)(pW0 + (nt * 8 + kt) * 512 + lane * 8));
            c0 = __builtin_amdgcn_mfma_f32_16x16x32_bf16(a[0][kt], b, c0, 0, 0, 0);
            c1 = __builtin_amdgcn_mfma_f32_16x16x32_bf16(a[1][kt], b, c1, 0, 0, 0);
        }
        float bias = b0[nt * 16 + l15];
        #pragma unroll
        for (int i = 0; i < 4; ++i) {
            sX[(base +      quad * 4 + i) * XS + nt * 16 + l15] = f2bf(fmaxf(c0[i] + bias, 0.f));
            sX[(base + 16 + quad * 4 + i) * XS + nt * 16 + l15] = f2bf(fmaxf(c1[i] + bias, 0.f));
        }
    }

    // layer 1 A-frags from H (same rows, in-wave ordered: no barrier needed)
    #pragma unroll
    for (int mt = 0; mt < 2; ++mt)
        #pragma unroll
        for (int kt = 0; kt < 8; ++kt)
            a[mt][kt] = __builtin_bit_cast(bf16x8, *(const u16x8*)(&sX[arow0 + mt * 16 * XS + kt * 32]));

    // destinations for this lane's rows (sorted: non-decreasing over consecutive edges)
    int tI[2][4];
    #pragma unroll
    for (int mt = 0; mt < 2; ++mt)
        #pragma unroll
        for (int i = 0; i < 4; ++i)
            tI[mt][i] = st[e0 + base + mt * 16 + quad * 4 + i];

    // layer 1: m = relu(H @ W1 + b1); run-dedup scatter-add into agg
    for (int nt = 0; nt < 8; ++nt) {
        f32x4 c0 = {0.f, 0.f, 0.f, 0.f}, c1 = {0.f, 0.f, 0.f, 0.f};
        #pragma unroll
        for (int kt = 0; kt < 8; ++kt) {
            bf16x8 b = __builtin_bit_cast(bf16x8, *(const u16x8*)(pW1 + (nt * 8 + kt) * 512 + lane * 8));
            c0 = __builtin_amdgcn_mfma_f32_16x16x32_bf16(a[0][kt], b, c0, 0, 0, 0);
            c1 = __builtin_amdgcn_mfma_f32_16x16x32_bf16(a[1][kt], b, c1, 0, 0, 0);
        }
        float bias = b1[nt * 16 + l15];
        int col = nt * 16 + l15;
        // run 0: rows base+quad*4+0..3 (consecutive sorted edges)
        {
            float acc = fmaxf(c0[0] + bias, 0.f);
            #pragma unroll
            for (int i = 1; i < 4; ++i) {
                float v = fmaxf(c0[i] + bias, 0.f);
                if (tI[0][i] == tI[0][i - 1]) acc += v;
                else { unsafeAtomicAdd(&agg[(size_t)tI[0][i - 1] * DD + col], acc); acc = v; }
            }
            unsafeAtomicAdd(&agg[(size_t)tI[0][3] * DD + col], acc);
        }
        // run 1: rows base+16+quad*4+0..3
        {
            float acc = fmaxf(c1[0] + bias, 0.f);
            #pragma unroll
            for (int i = 1; i < 4; ++i) {
                float v = fmaxf(c1[i] + bias, 0.f);
                if (tI[1][i] == tI[1][i - 1]) acc += v;
                else { unsafeAtomicAdd(&agg[(size_t)tI[1][i - 1] * DD + col], acc); acc = v; }
            }
            unsafeAtomicAdd(&agg[(size_t)tI[1][3] * DD + col], acc);
        }
    }
}

// Node update: out = nf + relu(relu([agg|nf] @ uW0 + ub0) @ uW1 + ub1)   (unchanged, validated)
__global__ __launch_bounds__(128) void k_update(
    const float* __restrict__ agg, const u16* __restrict__ nf16,
    const float* __restrict__ nf32, const u16* __restrict__ pW0,
    const float* __restrict__ b0, const u16* __restrict__ pW1,
    const float* __restrict__ b1, float* __restrict__ out)
{
    __shared__ u16 sX[64 * XS];
    const int tid = threadIdx.x;
    const int n0 = blockIdx.x * 64;

    // stage agg half (cols 0..127), fp32->bf16
    #pragma unroll
    for (int i = 0; i < 16; ++i) {
        int c = i * 128 + tid;
        int r = c >> 5, j = c & 31;
        int n = n0 + r;
        u16x4 o;
        if (n < NN) {
            float4 v = *(const float4*)(agg + (size_t)n * DD + j * 4);
            o[0] = f2bf(v.x); o[1] = f2bf(v.y); o[2] = f2bf(v.z); o[3] = f2bf(v.w);
        } else { o[0] = 0; o[1] = 0; o[2] = 0; o[3] = 0; }
        *(u16x4*)(&sX[r * XS + j * 4]) = o;
    }
    // stage nf half (cols 128..255), bf16 copy
    #pragma unroll
    for (int i = 0; i < 8; ++i) {
        int c = i * 128 + tid;
        int r = c >> 4, j = c & 15;
        int n = n0 + r;
        u16x8 v = {0, 0, 0, 0, 0, 0, 0, 0};
        if (n < NN) v = *(const u16x8*)(nf16 + (size_t)n * DD + j * 8);
        *(u16x8*)(&sX[r * XS + 128 + j * 8]) = v;
    }
    __syncthreads();

    const int lane = tid & 63;
    const int wave = tid >> 6;
    const int base = wave * 32;
    const int l15  = lane & 15;
    const int quad = lane >> 4;
    const int arow0 = (base + l15) * XS + quad * 8;

    bf16x8 a[2][8];
    #pragma unroll
    for (int mt = 0; mt < 2; ++mt)
        #pragma unroll
        for (int kt = 0; kt < 8; ++kt)
            a[mt][kt] = __builtin_bit_cast(bf16x8, *(const u16x8*)(&sX[arow0 + mt * 16 * XS + kt * 32]));

    for (int nt = 0; nt < 16; ++nt) {
        f32x4 c0 = {0.f, 0.f, 0.f, 0.f}, c1 = {0.f, 0.f, 0.f, 0.f};
        #pragma unroll
        for (int kt = 0; kt < 8; ++kt) {
            bf16x8 b = __builtin_bit_cast(bf16x8, *(const u16x8*)(pW0 + (nt * 8 + kt) * 512 + lane * 8));
            c0 = __builtin_amdgcn_mfma_f32_16x16x32_bf16(a[0][kt], b, c0, 0, 0, 0);
            c1 = __builtin_amdgcn_mfma_f32_16x16x32_bf16(a[1][kt], b, c1, 0, 0, 0);
        }
        float bias = b0[nt * 16 + l15];
        #pragma unroll
        for (int i = 0; i < 4; ++i) {
            sX[(base +      quad * 4 + i) * XS + nt * 16 + l15] = f2bf(fmaxf(c0[i] + bias, 0.f));
            sX[(base + 16 + quad * 4 + i) * XS + nt * 16 + l15] = f2bf(fmaxf(c1[i] + bias, 0.f));
        }
    }

    #pragma unroll
    for (int mt = 0; mt < 2; ++mt)
        #pragma unroll
        for (int kt = 0; kt < 8; ++kt)
            a[mt][kt] = __builtin_bit_cast(bf16x8, *(const u16x8*)(&sX[arow0 + mt * 16 * XS + kt * 32]));

    for (int nt = 0; nt < 8; ++nt) {
        f32x4 c0 = {0.f, 0.f, 0.f, 0.f}, c1 = {0.f, 0.f, 0.f, 0.f};
        #pragma unroll
        for (int kt = 0; kt < 8; ++kt) {
            bf16x8 b = __builtin_bit_cast(bf16x8, *(const u16x8*)(pW1 + (nt * 8 + kt) * 512 + lane * 8));
            c0 = __builtin_amdgcn_mfma_f32_16x16x32_bf16(a[0][kt], b, c0, 0, 0, 0);
            c1 = __builtin_amdgcn_mfma_f32_16x16x32_bf16(a[1][kt], b, c1, 0, 0, 0);
        }
        float bias = b1[nt * 16 + l15];
        int col = nt * 16 + l15;
        #pragma unroll
        for (int i = 0; i < 4; ++i) {
            int na = n0 + base +      quad * 4 + i;
            int nb = n0 + base + 16 + quad * 4 + i;
            if (na < NN) out[(size_t)na * DD + col] = nf32[(size_t)na * DD + col] + fmaxf(c0[i] + bias, 0.f);
            if (nb < NN) out[(size_t)nb * DD + col] = nf32[(size_t)nb * DD + col] + fmaxf(c1[i] + bias, 0.f);
        }
    }
}

extern "C" void kernel_launch(void* const* d_in, const int* in_sizes, int n_in,
                              void* d_out, int out_size, void* d_ws, size_t ws_size,
                              hipStream_t stream)
{
    const float* nf  = (const float*)d_in[0];
    const int* fidx  = (const int*)d_in[1];
    const int* tidx  = (const int*)d_in[2];
    const float* mW0 = (const float*)d_in[3];
    const float* mb0 = (const float*)d_in[4];
    const float* mW1 = (const float*)d_in[5];
    const float* mb1 = (const float*)d_in[6];
    const float* uW0 = (const float*)d_in[7];
    const float* ub0 = (const float*)d_in[8];
    const float* uW1 = (const float*)d_in[9];
    const float* ub1 = (const float*)d_in[10];
    float* out = (float*)d_out;

    char* ws = (char*)d_ws;
    u16*   nf16 = (u16*)ws;   ws += (size_t)NN * DD * 2;   // 12.8 MB
    float* agg  = (float*)ws; ws += (size_t)NN * DD * 4;   // 25.6 MB
    u16*   pmW0 = (u16*)ws;   ws += 256 * 256 * 2;
    u16*   pmW1 = (u16*)ws;   ws += 256 * 128 * 2;
    u16*   puW0 = (u16*)ws;   ws += 256 * 256 * 2;
    u16*   puW1 = (u16*)ws;   ws += 256 * 128 * 2;
    int*   cnt    = (int*)ws; ws += (size_t)NN * 4;        // 0.2 MB
    int*   cursor = (int*)ws; ws += (size_t)NN * 4;        // 0.2 MB
    int*   sf     = (int*)ws; ws += (size_t)NE * 4;        // 2.4 MB
    int*   st     = (int*)ws; ws += (size_t)NE * 4;        // 2.4 MB

    hipMemsetAsync(agg, 0, (size_t)NN * DD * 4, stream);
    hipMemsetAsync(cnt, 0, (size_t)NN * 4, stream);
    k_convert_nf<<<(NN * DD / 4) / 256, 256, 0, stream>>>(nf, nf16);
    k_pack<<<256, 256, 0, stream>>>(mW0, pmW0, 256, 256);
    k_pack<<<128, 256, 0, stream>>>(mW1, pmW1, 256, 128);
    k_pack<<<256, 256, 0, stream>>>(uW0, puW0, 256, 256);
    k_pack<<<128, 256, 0, stream>>>(uW1, puW1, 256, 128);
    k_hist<<<(NE + 255) / 256, 256, 0, stream>>>(tidx, cnt);
    k_scan<<<1, 1024, 0, stream>>>(cnt, cursor);
    k_reorder<<<(NE + 255) / 256, 256, 0, stream>>>(fidx, tidx, cursor, sf, st);
    k_edges<<<NE / 64, 128, 0, stream>>>(nf16, sf, st, pmW0, mb0, pmW1, mb1, agg);
    k_update<<<(NN + 63) / 64, 128, 0, stream>>>(agg, nf16, nf, puW0, ub0, puW1, ub1, out);
}

// Round 7
// 511.688 us; speedup vs baseline: 1.2808x; 1.1525x over previous
//
#include <hip/hip_runtime.h>

#define NN 50000
#define NE 600000
#define DD 128
#define XS 264   // padded LDS row stride in bf16 elems: 528 B = 33*16 (16B aligned), %32-dword offset 4 -> 2-way bank alias (free)
#define NB 49    // scan blocks: ceil(NN/1024)

typedef unsigned short u16;
typedef u16   u16x8  __attribute__((ext_vector_type(8)));
typedef u16   u16x4  __attribute__((ext_vector_type(4)));
typedef __bf16 bf16x8 __attribute__((ext_vector_type(8)));
typedef float f32x4  __attribute__((ext_vector_type(4)));

__device__ __forceinline__ u16 f2bf(float f) {  // RNE fp32->bf16
    unsigned u = __builtin_bit_cast(unsigned, f);
    u += 0x7FFFu + ((u >> 16) & 1u);
    return (u16)(u >> 16);
}

// node_features fp32 [NN,DD] -> bf16 table
__global__ void k_convert_nf(const float* __restrict__ nf, u16* __restrict__ out) {
    int id = blockIdx.x * 256 + threadIdx.x;            // NN*DD/4 threads exactly
    float4 v = ((const float4*)nf)[id];
    u16x4 o; o[0] = f2bf(v.x); o[1] = f2bf(v.y); o[2] = f2bf(v.z); o[3] = f2bf(v.w);
    ((u16x4*)out)[id] = o;
}

// Pack W[K,N] fp32 row-major into MFMA B-fragment order for 16x16x32
__global__ void k_pack(const float* __restrict__ W, u16* __restrict__ out, int K, int N) {
    int tid = blockIdx.x * 256 + threadIdx.x;
    if (tid >= K * N) return;
    int frag = tid >> 9, lane = (tid >> 3) & 63, j = tid & 7;
    int KT = K >> 5;
    int nt = frag / KT, kt = frag - nt * KT;
    int row = kt * 32 + ((lane >> 4) << 3) + j;
    int col = nt * 16 + (lane & 15);
    out[tid] = f2bf(W[row * N + col]);
}

// ---------------- counting sort of edges by destination (multi-block scan) ----------------
__global__ void k_hist(const int* __restrict__ to_idx, int* __restrict__ cnt) {
    int e = blockIdx.x * 256 + threadIdx.x;
    if (e < NE) atomicAdd(&cnt[to_idx[e]], 1);
}

// stage A: per-block (1024-elem) exclusive scan + block sum
__global__ void k_scanA(const int* __restrict__ cnt, int* __restrict__ part, int* __restrict__ bsum) {
    __shared__ int s[1024];
    int tid = threadIdx.x;
    int g = blockIdx.x * 1024 + tid;
    int v = (g < NN) ? cnt[g] : 0;
    s[tid] = v;
    __syncthreads();
    for (int ofs = 1; ofs < 1024; ofs <<= 1) {
        int t = (tid >= ofs) ? s[tid - ofs] : 0;
        __syncthreads();
        s[tid] += t;
        __syncthreads();
    }
    if (g < NN) part[g] = s[tid] - v;           // exclusive within block
    if (tid == 1023) bsum[blockIdx.x] = s[1023];
}

// stage B: exclusive scan of NB block sums (one tiny block)
__global__ void k_scanB(int* __restrict__ bsum) {
    __shared__ int s[64];
    int tid = threadIdx.x;
    int v = (tid < NB) ? bsum[tid] : 0;
    s[tid] = v;
    __syncthreads();
    for (int ofs = 1; ofs < 64; ofs <<= 1) {
        int t = (tid >= ofs) ? s[tid - ofs] : 0;
        __syncthreads();
        s[tid] += t;
        __syncthreads();
    }
    if (tid < NB) bsum[tid] = s[tid] - v;       // exclusive
}

// stage C: cursor = part + scanned block offset
__global__ void k_scanC(const int* __restrict__ part, const int* __restrict__ bsum, int* __restrict__ cursor) {
    int g = blockIdx.x * 256 + threadIdx.x;
    if (g < NN) cursor[g] = part[g] + bsum[g >> 10];
}

__global__ void k_reorder(const int* __restrict__ from_idx, const int* __restrict__ to_idx,
                          int* __restrict__ cursor, int* __restrict__ sf, int* __restrict__ st) {
    int e = blockIdx.x * 256 + threadIdx.x;
    if (e < NE) {
        int d = to_idx[e];
        int p = atomicAdd(&cursor[d], 1);
        sf[p] = from_idx[e];
        st[p] = d;
    }
}

// ---------------- edge kernel v5 (validated 295us): v1 geometry on dest-sorted edges ----------------
// 64 edges/block, 128 threads (2 waves), wave owns 32 rows. Sorted edges => each lane's 4
// consecutive rows mostly share a destination (avg run 12): register run-dedup collapses
// atomics ~2.3x (WRITE 300->131 MB measured) and clusters remaining atomics temporally.
__global__ __launch_bounds__(128) void k_edges(
    const u16* __restrict__ nf16, const int* __restrict__ sf,
    const int* __restrict__ st, const u16* __restrict__ pW0,
    const float* __restrict__ b0, const u16* __restrict__ pW1,
    const float* __restrict__ b1, float* __restrict__ agg)
{
    __shared__ u16 sX[64 * XS];
    const int tid = threadIdx.x;
    const int e0 = blockIdx.x * 64;

    // stage gather: 64 rows x 32 chunks of 8 bf16 (16 B); to-side rows repeat (sorted) -> cache-hot
    #pragma unroll
    for (int i = 0; i < 16; ++i) {
        int c = i * 128 + tid;
        int r = c >> 5, j = c & 31;
        int e = e0 + r;
        int node = (j < 16) ? sf[e] : st[e];
        *(u16x8*)(&sX[r * XS + j * 8]) = *(const u16x8*)(nf16 + node * DD + (j & 15) * 8);
    }
    __syncthreads();

    const int lane = tid & 63;
    const int wave = tid >> 6;
    const int base = wave * 32;
    const int l15  = lane & 15;
    const int quad = lane >> 4;
    const int arow0 = (base + l15) * XS + quad * 8;

    // consume X fully into registers (A-frags), freeing sX rows for H (rows wave-private)
    bf16x8 a[2][8];
    #pragma unroll
    for (int mt = 0; mt < 2; ++mt)
        #pragma unroll
        for (int kt = 0; kt < 8; ++kt)
            a[mt][kt] = __builtin_bit_cast(bf16x8, *(const u16x8*)(&sX[arow0 + mt * 16 * XS + kt * 32]));

    // layer 0: H[64,256] = relu(X @ W0 + b0)
    for (int nt = 0; nt < 16; ++nt) {
        f32x4 c0 = {0.f, 0.f, 0.f, 0.f}, c1 = {0.f, 0.f, 0.f, 0.f};
        #pragma unroll
        for (int kt = 0; kt < 8; ++kt) {
            bf16x8 b = __builtin_bit_cast(bf16x8, *(const u16x8*)(pW0 + (nt * 8 + kt) * 512 + lane * 8));
            c0 = __builtin_amdgcn_mfma_f32_16x16x32_bf16(a[0][kt], b, c0, 0, 0, 0);
            c1 = __builtin_amdgcn_mfma_f32_16x16x32_bf16(a[1][kt], b, c1, 0, 0, 0);
        }
        float bias = b0[nt * 16 + l15];
        #pragma unroll
        for (int i = 0; i < 4; ++i) {
            sX[(base +      quad * 4 + i) * XS + nt * 16 + l15] = f2bf(fmaxf(c0[i] + bias, 0.f));
            sX[(base + 16 + quad * 4 + i) * XS + nt * 16 + l15] = f2bf(fmaxf(c1[i] + bias, 0.f));
        }
    }

    // layer 1 A-frags from H (same rows, in-wave ordered: no barrier needed)
    #pragma unroll
    for (int mt = 0; mt < 2; ++mt)
        #pragma unroll
        for (int kt = 0; kt < 8; ++kt)
            a[mt][kt] = __builtin_bit_cast(bf16x8, *(const u16x8*)(&sX[arow0 + mt * 16 * XS + kt * 32]));

    // destinations for this lane's rows (sorted: non-decreasing over consecutive edges)
    int tI[2][4];
    #pragma unroll
    for (int mt = 0; mt < 2; ++mt)
        #pragma unroll
        for (int i = 0; i < 4; ++i)
            tI[mt][i] = st[e0 + base + mt * 16 + quad * 4 + i];

    // layer 1: m = relu(H @ W1 + b1); run-dedup scatter-add into agg
    for (int nt = 0; nt < 8; ++nt) {
        f32x4 c0 = {0.f, 0.f, 0.f, 0.f}, c1 = {0.f, 0.f, 0.f, 0.f};
        #pragma unroll
        for (int kt = 0; kt < 8; ++kt) {
            bf16x8 b = __builtin_bit_cast(bf16x8, *(const u16x8*)(pW1 + (nt * 8 + kt) * 512 + lane * 8));
            c0 = __builtin_amdgcn_mfma_f32_16x16x32_bf16(a[0][kt], b, c0, 0, 0, 0);
            c1 = __builtin_amdgcn_mfma_f32_16x16x32_bf16(a[1][kt], b, c1, 0, 0, 0);
        }
        float bias = b1[nt * 16 + l15];
        int col = nt * 16 + l15;
        // run 0: rows base+quad*4+0..3 (consecutive sorted edges)
        {
            float acc = fmaxf(c0[0] + bias, 0.f);
            #pragma unroll
            for (int i = 1; i < 4; ++i) {
                float v = fmaxf(c0[i] + bias, 0.f);
                if (tI[0][i] == tI[0][i - 1]) acc += v;
                else { unsafeAtomicAdd(&agg[(size_t)tI[0][i - 1] * DD + col], acc); acc = v; }
            }
            unsafeAtomicAdd(&agg[(size_t)tI[0][3] * DD + col], acc);
        }
        // run 1: rows base+16+quad*4+0..3
        {
            float acc = fmaxf(c1[0] + bias, 0.f);
            #pragma unroll
            for (int i = 1; i < 4; ++i) {
                float v = fmaxf(c1[i] + bias, 0.f);
                if (tI[1][i] == tI[1][i - 1]) acc += v;
                else { unsafeAtomicAdd(&agg[(size_t)tI[1][i - 1] * DD + col], acc); acc = v; }
            }
            unsafeAtomicAdd(&agg[(size_t)tI[1][3] * DD + col], acc);
        }
    }
}

// Node update: out = nf + relu(relu([agg|nf] @ uW0 + ub0) @ uW1 + ub1)   (unchanged, validated)
__global__ __launch_bounds__(128) void k_update(
    const float* __restrict__ agg, const u16* __restrict__ nf16,
    const float* __restrict__ nf32, const u16* __restrict__ pW0,
    const float* __restrict__ b0, const u16* __restrict__ pW1,
    const float* __restrict__ b1, float* __restrict__ out)
{
    __shared__ u16 sX[64 * XS];
    const int tid = threadIdx.x;
    const int n0 = blockIdx.x * 64;

    // stage agg half (cols 0..127), fp32->bf16
    #pragma unroll
    for (int i = 0; i < 16; ++i) {
        int c = i * 128 + tid;
        int r = c >> 5, j = c & 31;
        int n = n0 + r;
        u16x4 o;
        if (n < NN) {
            float4 v = *(const float4*)(agg + (size_t)n * DD + j * 4);
            o[0] = f2bf(v.x); o[1] = f2bf(v.y); o[2] = f2bf(v.z); o[3] = f2bf(v.w);
        } else { o[0] = 0; o[1] = 0; o[2] = 0; o[3] = 0; }
        *(u16x4*)(&sX[r * XS + j * 4]) = o;
    }
    // stage nf half (cols 128..255), bf16 copy
    #pragma unroll
    for (int i = 0; i < 8; ++i) {
        int c = i * 128 + tid;
        int r = c >> 4, j = c & 15;
        int n = n0 + r;
        u16x8 v = {0, 0, 0, 0, 0, 0, 0, 0};
        if (n < NN) v = *(const u16x8*)(nf16 + (size_t)n * DD + j * 8);
        *(u16x8*)(&sX[r * XS + 128 + j * 8]) = v;
    }
    __syncthreads();

    const int lane = tid & 63;
    const int wave = tid >> 6;
    const int base = wave * 32;
    const int l15  = lane & 15;
    const int quad = lane >> 4;
    const int arow0 = (base + l15) * XS + quad * 8;

    bf16x8 a[2][8];
    #pragma unroll
    for (int mt = 0; mt < 2; ++mt)
        #pragma unroll
        for (int kt = 0; kt < 8; ++kt)
            a[mt][kt] = __builtin_bit_cast(bf16x8, *(const u16x8*)(&sX[arow0 + mt * 16 * XS + kt * 32]));

    for (int nt = 0; nt < 16; ++nt) {
        f32x4 c0 = {0.f, 0.f, 0.f, 0.f}, c1 = {0.f, 0.f, 0.f, 0.f};
        #pragma unroll
        for (int kt = 0; kt < 8; ++kt) {
            bf16x8 b = __builtin_bit_cast(bf16x8, *(const u16x8*)(pW0 + (nt * 8 + kt) * 512 + lane * 8));
            c0 = __builtin_amdgcn_mfma_f32_16x16x32_bf16(a[0][kt], b, c0, 0, 0, 0);
            c1 = __builtin_amdgcn_mfma_f32_16x16x32_bf16(a[1][kt], b, c1, 0, 0, 0);
        }
        float bias = b0[nt * 16 + l15];
        #pragma unroll
        for (int i = 0; i < 4; ++i) {
            sX[(base +      quad * 4 + i) * XS + nt * 16 + l15] = f2bf(fmaxf(c0[i] + bias, 0.f));
            sX[(base + 16 + quad * 4 + i) * XS + nt * 16 + l15] = f2bf(fmaxf(c1[i] + bias, 0.f));
        }
    }

    #pragma unroll
    for (int mt = 0; mt < 2; ++mt)
        #pragma unroll
        for (int kt = 0; kt < 8; ++kt)
            a[mt][kt] = __builtin_bit_cast(bf16x8, *(const u16x8*)(&sX[arow0 + mt * 16 * XS + kt * 32]));

    for (int nt = 0; nt < 8; ++nt) {
        f32x4 c0 = {0.f, 0.f, 0.f, 0.f}, c1 = {0.f, 0.f, 0.f, 0.f};
        #pragma unroll
        for (int kt = 0; kt < 8; ++kt) {
            bf16x8 b = __builtin_bit_cast(bf16x8, *(const u16x8*)(pW1 + (nt * 8 + kt) * 512 + lane * 8));
            c0 = __builtin_amdgcn_mfma_f32_16x16x32_bf16(a[0][kt], b, c0, 0, 0, 0);
            c1 = __builtin_amdgcn_mfma_f32_16x16x32_bf16(a[1][kt], b, c1, 0, 0, 0);
        }
        float bias = b1[nt * 16 + l15];
        int col = nt * 16 + l15;
        #pragma unroll
        for (int i = 0; i < 4; ++i) {
            int na = n0 + base +      quad * 4 + i;
            int nb = n0 + base + 16 + quad * 4 + i;
            if (na < NN) out[(size_t)na * DD + col] = nf32[(size_t)na * DD + col] + fmaxf(c0[i] + bias, 0.f);
            if (nb < NN) out[(size_t)nb * DD + col] = nf32[(size_t)nb * DD + col] + fmaxf(c1[i] + bias, 0.f);
        }
    }
}

extern "C" void kernel_launch(void* const* d_in, const int* in_sizes, int n_in,
                              void* d_out, int out_size, void* d_ws, size_t ws_size,
                              hipStream_t stream)
{
    const float* nf  = (const float*)d_in[0];
    const int* fidx  = (const int*)d_in[1];
    const int* tidx  = (const int*)d_in[2];
    const float* mW0 = (const float*)d_in[3];
    const float* mb0 = (const float*)d_in[4];
    const float* mW1 = (const float*)d_in[5];
    const float* mb1 = (const float*)d_in[6];
    const float* uW0 = (const float*)d_in[7];
    const float* ub0 = (const float*)d_in[8];
    const float* uW1 = (const float*)d_in[9];
    const float* ub1 = (const float*)d_in[10];
    float* out = (float*)d_out;

    char* ws = (char*)d_ws;
    u16*   nf16 = (u16*)ws;   ws += (size_t)NN * DD * 2;   // 12.8 MB
    float* agg  = (float*)ws; ws += (size_t)NN * DD * 4;   // 25.6 MB
    u16*   pmW0 = (u16*)ws;   ws += 256 * 256 * 2;
    u16*   pmW1 = (u16*)ws;   ws += 256 * 128 * 2;
    u16*   puW0 = (u16*)ws;   ws += 256 * 256 * 2;
    u16*   puW1 = (u16*)ws;   ws += 256 * 128 * 2;
    int*   cnt    = (int*)ws; ws += (size_t)NN * 4;        // 0.2 MB
    int*   cursor = (int*)ws; ws += (size_t)NN * 4;        // 0.2 MB
    int*   part   = (int*)ws; ws += (size_t)NN * 4;        // 0.2 MB
    int*   bsum   = (int*)ws; ws += 64 * 4;
    int*   sf     = (int*)ws; ws += (size_t)NE * 4;        // 2.4 MB
    int*   st     = (int*)ws; ws += (size_t)NE * 4;        // 2.4 MB

    hipMemsetAsync(agg, 0, (size_t)NN * DD * 4, stream);
    hipMemsetAsync(cnt, 0, (size_t)NN * 4, stream);
    k_convert_nf<<<(NN * DD / 4) / 256, 256, 0, stream>>>(nf, nf16);
    k_pack<<<256, 256, 0, stream>>>(mW0, pmW0, 256, 256);
    k_pack<<<128, 256, 0, stream>>>(mW1, pmW1, 256, 128);
    k_pack<<<256, 256, 0, stream>>>(uW0, puW0, 256, 256);
    k_pack<<<128, 256, 0, stream>>>(uW1, puW1, 256, 128);
    k_hist<<<(NE + 255) / 256, 256, 0, stream>>>(tidx, cnt);
    k_scanA<<<NB, 1024, 0, stream>>>(cnt, part, bsum);
    k_scanB<<<1, 64, 0, stream>>>(bsum);
    k_scanC<<<(NN + 255) / 256, 256, 0, stream>>>(part, bsum, cursor);
    k_reorder<<<(NE + 255) / 256, 256, 0, stream>>>(fidx, tidx, cursor, sf, st);
    k_edges<<<NE / 64, 128, 0, stream>>>(nf16, sf, st, pmW0, mb0, pmW1, mb1, agg);
    k_update<<<(NN + 63) / 64, 128, 0, stream>>>(agg, nf16, nf, puW0, ub0, puW1, ub1, out);
}